// Round 1
// baseline (87.607 us; speedup 1.0000x reference)
//
#include <hip/hip_runtime.h>

#define HH 64
#define WW 64
#define TT 16
#define NPIX (HH * WW * TT)   // 65536

__global__ __launch_bounds__(256) void statdenoise_kernel(
    const float* __restrict__ img,
    const float* __restrict__ gui,
    const float* __restrict__ est,
    const float* __restrict__ var,
    float* __restrict__ out)
{
    const float SIG[9] = {0.1f, 0.1f, 0.1f, 50.0f, 50.0f, 50.0f, 10.0f, 10.0f, 10.0f};
    const float G2 = 2.907f * 2.907f;   // gamma^2

    int idx = blockIdx.x * 256 + threadIdx.x;   // idx == (h*64 + w)*16 + t
    int t = idx & 15;
    int w = (idx >> 4) & 63;
    int h = idx >> 10;

    // center values in registers
    float gc[9];
#pragma unroll
    for (int c = 0; c < 9; ++c) gc[c] = gui[c * NPIX + idx];
    float ec[3], vc[3];
#pragma unroll
    for (int c = 0; c < 3; ++c) {
        ec[c] = est[c * NPIX + idx];
        vc[c] = var[c * NPIX + idx];
    }

    float acc0 = 0.f, acc1 = 0.f, acc2 = 0.f, wsum = 0.f;

    for (int dh = -3; dh <= 3; ++dh) {
        int hh = h + dh;
        if ((unsigned)hh >= (unsigned)HH) continue;
        for (int dw = -3; dw <= 3; ++dw) {
            int ww = w + dw;
            if ((unsigned)ww >= (unsigned)WW) continue;
#pragma unroll
            for (int dt = -1; dt <= 1; ++dt) {
                int tt = t + dt;
                if ((unsigned)tt >= (unsigned)TT) continue;
                // In-bounds neighbor. (OOB neighbors provably have zero weight:
                // vj==0 & ej!=ei -> w_ij=1 -> t=inf -> membership=0.)
                int nb = ((hh << 6) + ww) * 16 + tt;

                // bilateral range weight over 9 guidance channels
                float s = 0.f;
#pragma unroll
                for (int c = 0; c < 9; ++c) {
                    float d = gui[c * NPIX + nb] - gc[c];
                    s = fmaf(d * d, SIG[c], s);
                }
                float bil = __expf(-0.5f * s);

                // Welch-style t-test membership over 3 estimand channels
                bool mem = true;
#pragma unroll
                for (int c = 0; c < 3; ++c) {
                    float ej = est[c * NPIX + nb];
                    float vj = var[c * NPIX + nb];
                    float d  = ec[c] - ej;
                    float d2 = d * d;
                    float num = 2.f * d2 + vc[c] + vj;
                    float den = 2.f * (d2 + vc[c] + vj);
                    float wij = num / (den == 0.f ? 1.f : den);
                    if (num == 0.f && den == 0.f) wij = 0.5f;
                    if ((vc[c] == 0.f || vj == 0.f) && ec[c] != ej) wij = 1.0f;
                    float arg = fmaxf(1.f / (2.f * (1.f - wij)) - 1.f, 0.f);
                    mem = mem && (wij != 1.0f) && (arg < G2);
                }
                if (dh == 0 && dw == 0 && dt == 0) mem = true;   // center forced member

                float wt = mem ? bil : 0.f;
                wsum += wt;
                acc0 = fmaf(img[0 * NPIX + nb], wt, acc0);
                acc1 = fmaf(img[1 * NPIX + nb], wt, acc1);
                acc2 = fmaf(img[2 * NPIX + nb], wt, acc2);
            }
        }
    }

    float inv = 1.f / wsum;   // wsum >= 1 (center weight is exactly 1)
    out[0 * NPIX + idx] = acc0 * inv;
    out[1 * NPIX + idx] = acc1 * inv;
    out[2 * NPIX + idx] = acc2 * inv;
}

extern "C" void kernel_launch(void* const* d_in, const int* in_sizes, int n_in,
                              void* d_out, int out_size, void* d_ws, size_t ws_size,
                              hipStream_t stream) {
    const float* img = (const float*)d_in[0];
    const float* gui = (const float*)d_in[1];
    const float* est = (const float*)d_in[2];
    const float* var = (const float*)d_in[3];
    float* out = (float*)d_out;

    dim3 grid(NPIX / 256);
    dim3 block(256);
    statdenoise_kernel<<<grid, block, 0, stream>>>(img, gui, est, var, out);
}

// Round 2
// 34.646 us; speedup vs baseline: 2.5286x; 2.5286x over previous
//
#include <hip/hip_runtime.h>

#define HH 64
#define WW 64
#define TT 16
#define NPIX (HH * WW * TT)   // 65536

// Block = 64 pixels x 4 wave-uniform neighbor-splits.
// Split s handles (dh,dw) offsets with linear index r = (dh+3)*7+(dw+3), r % 4 == s.
__global__ __launch_bounds__(256) void statdenoise_kernel(
    const float* __restrict__ img,
    const float* __restrict__ gui,
    const float* __restrict__ est,
    const float* __restrict__ var,
    float* __restrict__ out)
{
    const float SIG[9] = {0.1f, 0.1f, 0.1f, 50.0f, 50.0f, 50.0f, 10.0f, 10.0f, 10.0f};
    const float G2 = 2.907f * 2.907f;   // gamma^2

    const int lane = threadIdx.x & 63;
    const int s    = threadIdx.x >> 6;          // 0..3, wave-uniform
    const int idx  = blockIdx.x * 64 + lane;    // 64 consecutive pixels per block
    const int t = idx & 15;
    const int w = (idx >> 4) & 63;
    const int h = idx >> 10;                    // block-uniform

    // center values (duplicated across the 4 splits; 15 loads, negligible)
    float gc[9];
#pragma unroll
    for (int c = 0; c < 9; ++c) gc[c] = gui[c * NPIX + idx];
    float ec[3], vc[3];
    bool  vzc[3];
#pragma unroll
    for (int c = 0; c < 3; ++c) {
        ec[c] = est[c * NPIX + idx];
        vc[c] = var[c * NPIX + idx];
        vzc[c] = (vc[c] == 0.0f);
    }

    float acc0 = 0.f, acc1 = 0.f, acc2 = 0.f, wsum = 0.f;

    // incremental walk over r = s, s+4, ..., <49 : dh = r/7-3, dw = r%7-3
    int dh = -3, dw = -3 + s;
    while (dh <= 3) {
        const int hh = h + dh;
        const int ww = w + dw;
        if (((unsigned)hh < (unsigned)HH) & ((unsigned)ww < (unsigned)WW)) {
            const int nbase = ((hh << 6) + ww) << 4;
            const bool centerCol = (dh == 0) & (dw == 0);   // only split 0 ever hits this
#pragma unroll
            for (int dt = -1; dt <= 1; ++dt) {
                const int tt = t + dt;
                if ((unsigned)tt >= (unsigned)TT) continue;
                // In-bounds neighbor. (OOB neighbors provably have zero weight:
                // vj==0 & ej!=ei -> w_ij=1 -> t=inf -> membership=0.)
                const int nb = nbase + tt;

                // bilateral range weight over 9 guidance channels
                float ssum = 0.f;
#pragma unroll
                for (int c = 0; c < 9; ++c) {
                    float d = gui[c * NPIX + nb] - gc[c];
                    ssum = fmaf(d * d, SIG[c], ssum);
                }
                float bil = __expf(-0.5f * ssum);

                // Welch t-test membership, division-free:
                //   arg = 1/(2(1-w)) - 1 == d^2 / (vi+vj)   (V>0)
                //   pass  <=> d^2 < gamma^2 * V,  plus exact special cases.
                bool mem = true;
#pragma unroll
                for (int c = 0; c < 3; ++c) {
                    float ej = est[c * NPIX + nb];
                    float vj = var[c * NPIX + nb];
                    float d  = ec[c] - ej;
                    float d2 = d * d;
                    float V  = vc[c] + vj;
                    bool pass = (d2 < G2 * V) | ((d2 == 0.f) & (V == 0.f));
                    bool kill = (vzc[c] | (vj == 0.f)) & (d2 != 0.f);
                    mem = mem & pass & (!kill);
                }
                if (centerCol && dt == 0) mem = true;   // center forced member

                float wt = mem ? bil : 0.f;
                wsum += wt;
                acc0 = fmaf(img[0 * NPIX + nb], wt, acc0);
                acc1 = fmaf(img[1 * NPIX + nb], wt, acc1);
                acc2 = fmaf(img[2 * NPIX + nb], wt, acc2);
            }
        }
        dw += 4;
        if (dw > 3) { dw -= 7; ++dh; }
    }

    // combine the 4 splits through LDS
    __shared__ float4 red[4][64];
    red[s][lane] = make_float4(acc0, acc1, acc2, wsum);
    __syncthreads();

    if (threadIdx.x < 64) {
        float4 a = red[0][lane];
        float4 b = red[1][lane];
        float4 c = red[2][lane];
        float4 d = red[3][lane];
        float A0 = a.x + b.x + c.x + d.x;
        float A1 = a.y + b.y + c.y + d.y;
        float A2 = a.z + b.z + c.z + d.z;
        float WS = a.w + b.w + c.w + d.w;   // >= 1 (center weight is exactly 1)
        float inv = 1.f / WS;
        out[0 * NPIX + idx] = A0 * inv;
        out[1 * NPIX + idx] = A1 * inv;
        out[2 * NPIX + idx] = A2 * inv;
    }
}

extern "C" void kernel_launch(void* const* d_in, const int* in_sizes, int n_in,
                              void* d_out, int out_size, void* d_ws, size_t ws_size,
                              hipStream_t stream) {
    const float* img = (const float*)d_in[0];
    const float* gui = (const float*)d_in[1];
    const float* est = (const float*)d_in[2];
    const float* var = (const float*)d_in[3];
    float* out = (float*)d_out;

    dim3 grid(NPIX / 64);   // 1024 blocks: 64 pixels x 4 splits each
    dim3 block(256);
    statdenoise_kernel<<<grid, block, 0, stream>>>(img, gui, est, var, out);
}

// Round 3
// 28.878 us; speedup vs baseline: 3.0337x; 1.1997x over previous
//
#include <hip/hip_runtime.h>

#define HH 64
#define WW 64
#define TT 16
#define NPIX (HH * WW * TT)   // 65536

// Block = 512 threads = 8 waves. Each wave is one neighbor-split s (columns
// r = s, s+8, ... < 49 of the 7x7 (dh,dw) grid). Within a wave: 8 (h,w)
// pixels x 8 t-groups; each thread owns t = {2*tg, 2*tg+1} (K=2 t-blocking).
// Per column each channel is loaded ONCE as an aligned float2 (coalesced
// 64B per hw); the t-halo values (t0-1, t0+2) come from lane shuffles.
__global__ __launch_bounds__(512) void statdenoise_kernel(
    const float* __restrict__ img,
    const float* __restrict__ gui,
    const float* __restrict__ est,
    const float* __restrict__ var,
    float* __restrict__ out)
{
    const float SIG[9] = {0.1f, 0.1f, 0.1f, 50.0f, 50.0f, 50.0f, 10.0f, 10.0f, 10.0f};
    const float G2 = 2.907f * 2.907f;   // gamma^2

    const int lane = threadIdx.x & 63;
    const int s    = threadIdx.x >> 6;          // wave id == split 0..7
    const int tg   = lane & 7;                  // t-group 0..7
    const int hwl  = lane >> 3;                 // 0..7
    const int hw   = blockIdx.x * 8 + hwl;      // 8 consecutive (h,w) per block
    const int h    = hw >> 6;                   // uniform per block
    const int w    = hw & 63;
    const int t0   = tg * 2;                    // owns t0, t0+1
    const int cpx  = hw * 16 + t0;

    // center values (float2 along t)
    float2 gc[9];
#pragma unroll
    for (int c = 0; c < 9; ++c) gc[c] = *(const float2*)&gui[c * NPIX + cpx];
    float2 ec[3], vc[3];
#pragma unroll
    for (int c = 0; c < 3; ++c) {
        ec[c] = *(const float2*)&est[c * NPIX + cpx];
        vc[c] = *(const float2*)&var[c * NPIX + cpx];
    }

    // t-halo validity: pair (e=0,dt=-1) needs t0-1; pair (e=1,dt=+1) needs t0+2.
    const bool vLo = (t0 != 0);        // exactly the lanes whose shfl_up crosses hw groups
    const bool vHi = (t0 != 14);

    float acc[2][4] = {};   // per owned t: {r,g,b,wsum}

    // (dh,dw) for r = s, then advance by 8 each iteration
    int dh = s / 7 - 3;
    int dw = s % 7 - 3;
    for (int r = s; r < 49; r += 8) {
        const int hh = h + dh;                       // wave-uniform
        if ((unsigned)hh < (unsigned)HH) {
            const int ww   = w + dw;                 // per-lane
            const bool colOK = (unsigned)ww < (unsigned)WW;
            const int wwc  = colOK ? ww : (ww < 0 ? 0 : WW - 1);   // clamp for safe loads
            const int off0 = (((hh << 6) + wwc) << 4) + t0;

            // ---- bilateral over 9 guidance channels, 6 pairs (e x dt) ----
            float sb[2][3] = {};
#pragma unroll
            for (int c = 0; c < 9; ++c) {
                const float* g = gui + c * NPIX;
                float2 m = *(const float2*)&g[off0];
                float lo = __shfl_up(m.y, 1);        // t0-1 (garbage at tg==0, masked)
                float hi = __shfl_down(m.x, 1);      // t0+2 (garbage at tg==7, masked)
                float nv[4] = {lo, m.x, m.y, hi};    // tt = t0-1+k
#pragma unroll
                for (int e = 0; e < 2; ++e) {
                    float ce = e ? gc[c].y : gc[c].x;
#pragma unroll
                    for (int k = 0; k < 3; ++k) {    // dt = k-1, neighbor = nv[e+k]
                        float d = ce - nv[e + k];
                        sb[e][k] = fmaf(d * d, SIG[c], sb[e][k]);
                    }
                }
            }

            // ---- membership (division-free Welch t-test), 3 channels ----
            bool mem[2][3] = {{true, true, true}, {true, true, true}};
#pragma unroll
            for (int c = 0; c < 3; ++c) {
                const float* ep = est + c * NPIX;
                const float* vp = var + c * NPIX;
                float2 em = *(const float2*)&ep[off0];
                float2 vm = *(const float2*)&vp[off0];
                float env[4] = {__shfl_up(em.y, 1), em.x, em.y, __shfl_down(em.x, 1)};
                float vnv[4] = {__shfl_up(vm.y, 1), vm.x, vm.y, __shfl_down(vm.x, 1)};
#pragma unroll
                for (int e = 0; e < 2; ++e) {
                    float ece = e ? ec[c].y : ec[c].x;
                    float vce = e ? vc[c].y : vc[c].x;
#pragma unroll
                    for (int k = 0; k < 3; ++k) {
                        float d  = ece - env[e + k];
                        float d2 = d * d;
                        float V  = vce + vnv[e + k];
                        bool pass = (d2 < G2 * V) | ((d2 == 0.f) & (V == 0.f));
                        bool kill = ((vce == 0.f) | (vnv[e + k] == 0.f)) & (d2 != 0.f);
                        mem[e][k] = mem[e][k] & pass & (!kill);
                    }
                }
            }

            // ---- weights ----
            float wt[2][3];
#pragma unroll
            for (int e = 0; e < 2; ++e) {
#pragma unroll
                for (int k = 0; k < 3; ++k) {
                    bool ok = colOK;
                    if (e == 0 && k == 0) ok = ok && vLo;   // tt = t0-1
                    if (e == 1 && k == 2) ok = ok && vHi;   // tt = t0+2
                    float b = __expf(-0.5f * sb[e][k]);
                    // center pair (dh==0,dw==0,dt==0) provably passes mem (d2==0),
                    // matching the reference's forced membership[CENTER]=1.
                    wt[e][k] = (ok && mem[e][k]) ? b : 0.f;
                }
            }

            // ---- accumulate image ----
#pragma unroll
            for (int c = 0; c < 3; ++c) {
                const float* ip = img + c * NPIX;
                float2 im = *(const float2*)&ip[off0];
                float inv[4] = {__shfl_up(im.y, 1), im.x, im.y, __shfl_down(im.x, 1)};
#pragma unroll
                for (int e = 0; e < 2; ++e) {
                    float a = 0.f;
#pragma unroll
                    for (int k = 0; k < 3; ++k) a = fmaf(wt[e][k], inv[e + k], a);
                    acc[e][c] += a;
                }
            }
#pragma unroll
            for (int e = 0; e < 2; ++e)
                acc[e][3] += wt[e][0] + wt[e][1] + wt[e][2];
        }
        dw += 8;
        while (dw > 3) { dw -= 7; ++dh; }
    }

    // ---- combine the 8 splits through LDS ----
    __shared__ float4 red[2][8][64];
    red[0][s][lane] = make_float4(acc[0][0], acc[0][1], acc[0][2], acc[0][3]);
    red[1][s][lane] = make_float4(acc[1][0], acc[1][1], acc[1][2], acc[1][3]);
    __syncthreads();

    if (threadIdx.x < 128) {
        const int j = threadIdx.x;
        const int l = j >> 1, e = j & 1;
        float4 sum = red[e][0][l];
#pragma unroll
        for (int q = 1; q < 8; ++q) {
            float4 v = red[e][q][l];
            sum.x += v.x; sum.y += v.y; sum.z += v.z; sum.w += v.w;
        }
        const int px = blockIdx.x * 128 + j;   // px_local == j by construction
        const float inv = 1.f / sum.w;         // wsum >= 1 (center weight is exactly 1)
        out[0 * NPIX + px] = sum.x * inv;
        out[1 * NPIX + px] = sum.y * inv;
        out[2 * NPIX + px] = sum.z * inv;
    }
}

extern "C" void kernel_launch(void* const* d_in, const int* in_sizes, int n_in,
                              void* d_out, int out_size, void* d_ws, size_t ws_size,
                              hipStream_t stream) {
    const float* img = (const float*)d_in[0];
    const float* gui = (const float*)d_in[1];
    const float* est = (const float*)d_in[2];
    const float* var = (const float*)d_in[3];
    float* out = (float*)d_out;

    dim3 grid(4096 / 8);    // 512 blocks: 8 (h,w) x 16 t pixels each, 8 splits
    dim3 block(512);
    statdenoise_kernel<<<grid, block, 0, stream>>>(img, gui, est, var, out);
}